// Round 5
// baseline (891.811 us; speedup 1.0000x reference)
//
#include <hip/hip_runtime.h>
#include <math.h>

typedef unsigned short u16;
typedef __attribute__((ext_vector_type(8))) short bf16x8;
typedef __attribute__((ext_vector_type(4))) float f32x4;
typedef const __attribute__((address_space(1))) unsigned int* gas_t;
typedef __attribute__((address_space(3))) unsigned int* las_t;

__device__ __forceinline__ float bf2f(u16 u) {
    unsigned x = ((unsigned)u) << 16; float f; __builtin_memcpy(&f, &x, 4); return f;
}
__device__ __forceinline__ u16 f2bf(float f) {
    unsigned x; __builtin_memcpy(&x, &f, 4);
    unsigned lsb = (x >> 16) & 1u; x += 0x7fffu + lsb; return (u16)(x >> 16);
}

// ---------------- input dtype detector (1 = f32 inputs) ----------------
__global__ __launch_bounds__(256) void k_detect(const u16* __restrict__ wq, int* __restrict__ flag) {
    const int tid = threadIdx.x;
    int cnt = 0;
    for (int i = tid; i < 2048; i += 256) {
        float v = fabsf(bf2f(wq[2 * i]));
        if (!(v < 1e4f) || (v != 0.f && v < 1e-30f)) cnt++;
    }
    for (int off = 32; off; off >>= 1) cnt += __shfl_down(cnt, off, 64);
    __shared__ int red[4];
    int lane = tid & 63, w = tid >> 6;
    if (!lane) red[w] = cnt;
    __syncthreads();
    if (!tid) flag[0] = (red[0] + red[1] + red[2] + red[3] > 204) ? 1 : 0;
}

// ---------------- small-vector convert: [bqkv|bgate|bproj|lng|lnb] -> bf16 ----------------
__global__ __launch_bounds__(256) void k_cvec(const void* __restrict__ bqkv, const void* __restrict__ bgate,
                                              const void* __restrict__ bproj, const void* __restrict__ lng,
                                              const void* __restrict__ lnb, const int* __restrict__ flag,
                                              u16* __restrict__ cv) {
    int i = blockIdx.x * 256 + threadIdx.x;   // 0..7167
    const void* src; int off;
    if (i < 3072)      { src = bqkv;  off = i; }
    else if (i < 4096) { src = bgate; off = i - 3072; }
    else if (i < 5120) { src = bproj; off = i - 4096; }
    else if (i < 6144) { src = lng;   off = i - 5120; }
    else               { src = lnb;   off = i - 6144; }
    cv[i] = flag[0] ? f2bf(((const float*)src)[off]) : ((const u16*)src)[off];
}

// ---------------- BK=64 async MFMA 128x128-tile K-loop ----------------
// LDS: two BK=32 half-tiles per operand: As = [2][128][32] u16 (8192 u16), same for Bs.
// One barrier pair per 64 k-elements (half the drains of BK=32).
__device__ __forceinline__ void gemm_loop(const u16* __restrict__ Ab, long ar0, long as_, long ka0,
                                          const u16* __restrict__ Bb, long br0, long bs_, long kb0,
                                          int ksteps, u16* As, u16* Bs, int tid, f32x4 acc[4][4]) {
    const int lane = tid & 63, wave = tid >> 6;
    const int waveM = (tid >> 7) & 1, waveN = (tid >> 6) & 1;
    const int quad = lane >> 4, l16 = lane & 15;
    const int rr = lane >> 2;          // row within 16-row chunk
    const int cc = (lane & 3) * 8;     // col within 32-col half (u16)
    const u16* gA[4]; const u16* gB[4]; u16* lA[4]; u16* lB[4];
#pragma unroll
    for (int i = 0; i < 4; ++i) {
        int g = wave * 4 + i, c = g & 7, h = g >> 3;
        gA[i] = Ab + (ar0 + c * 16 + rr) * as_ + ka0 + h * 32 + cc;
        gB[i] = Bb + (br0 + c * 16 + rr) * bs_ + kb0 + h * 32 + cc;
        lA[i] = As + h * 4096 + c * 512;   // wave-uniform base (+lane*16B implicit)
        lB[i] = Bs + h * 4096 + c * 512;
    }
    for (int kt = 0; kt < ksteps; ++kt) {
        const long ko = (long)kt * 64;
#pragma unroll
        for (int i = 0; i < 4; ++i) {
            __builtin_amdgcn_global_load_lds((gas_t)(gA[i] + ko), (las_t)lA[i], 16, 0, 0);
            __builtin_amdgcn_global_load_lds((gas_t)(gB[i] + ko), (las_t)lB[i], 16, 0, 0);
        }
        __syncthreads();   // drain -> both k-halves resident
#pragma unroll
        for (int sub = 0; sub < 2; ++sub) {
            const u16* Ah = As + sub * 4096; const u16* Bh = Bs + sub * 4096;
            bf16x8 af[4], bv[4];
#pragma unroll
            for (int mi = 0; mi < 4; ++mi)
                af[mi] = *(const bf16x8*)(Ah + (waveM * 64 + mi * 16 + l16) * 32 + quad * 8);
#pragma unroll
            for (int ni = 0; ni < 4; ++ni)
                bv[ni] = *(const bf16x8*)(Bh + (waveN * 64 + ni * 16 + l16) * 32 + quad * 8);
#pragma unroll
            for (int mi = 0; mi < 4; ++mi)
#pragma unroll
                for (int ni = 0; ni < 4; ++ni)
                    acc[mi][ni] = __builtin_amdgcn_mfma_f32_16x16x32_bf16(af[mi], bv[ni], acc[mi][ni], 0, 0, 0);
        }
        __syncthreads();
    }
}

#define EPI_COORDS \
    const int lane = tid & 63; const int quad = lane >> 4; const int l16 = lane & 15; \
    const int waveM = (tid >> 7) & 1; const int waveN = (tid >> 6) & 1;

#define ZERO_ACC(acc) \
    _Pragma("unroll") for (int mi = 0; mi < 4; ++mi) \
    _Pragma("unroll") for (int ni = 0; ni < 4; ++ni) acc[mi][ni] = (f32x4){0.f, 0.f, 0.f, 0.f};

// ---------------- tiled weight transpose into permuted Wt order ----------------
// Wt row n' layout: [0,1024)=q cols | [1024,2048)=v cols | [2048,4096)=16 pairs of (64 k-cols | 64 gate-cols)
__global__ __launch_bounds__(256) void k_transw(const void* __restrict__ wqkv, const void* __restrict__ wgate,
                                                const void* __restrict__ wproj, const int* __restrict__ flag,
                                                u16* __restrict__ Wt, u16* __restrict__ WpT) {
    const int bid = blockIdx.x, tid = threadIdx.x;   // 1280 blocks: 80 n-tiles x 16 k-tiles
    const int ktl = bid & 15, ntile = bid >> 4;
    const int n0 = ntile * 64, k0 = ktl * 64;
    const int fl = flag[0];
    const void* src; int ld, c0;
    if (n0 < 1024)      { src = wqkv;  ld = 3072; c0 = n0; }                       // q
    else if (n0 < 2048) { src = wqkv;  ld = 3072; c0 = 2048 + (n0 - 1024); }       // v
    else if (n0 < 4096) {
        int m = n0 - 2048; int p = m >> 7; int half = (m >> 6) & 1;
        if (half == 0) { src = wqkv;  ld = 3072; c0 = 1024 + p * 64; }             // k
        else           { src = wgate; ld = 1024; c0 = p * 64; }                    // gate
    } else              { src = wproj; ld = 1024; c0 = n0 - 4096; }
    __shared__ u16 t[64][66];
#pragma unroll
    for (int i = 0; i < 16; ++i) {
        int idx = tid + i * 256; int r = idx >> 6, c = idx & 63;   // r=k, c=n (local)
        long off = (long)(k0 + r) * ld + c0 + c;
        float v = fl ? ((const float*)src)[off] : bf2f(((const u16*)src)[off]);
        t[r][c] = f2bf(v);
    }
    __syncthreads();
#pragma unroll
    for (int i = 0; i < 16; ++i) {
        int idx = tid + i * 256; int r = idx >> 6, c = idx & 63;   // r=n, c=k (local)
        int n = n0 + r;
        if (n < 4096) Wt[(long)n * 1024 + k0 + c] = t[c][r];
        else          WpT[(long)(n - 4096) * 1024 + k0 + c] = t[c][r];
    }
}

// ---------------- LayerNorm ----------------
__global__ __launch_bounds__(256) void k_ln(const void* __restrict__ xin, const u16* __restrict__ cv,
                                            const int* __restrict__ flag, u16* __restrict__ XN) {
    const long t = blockIdx.x; const int tid = threadIdx.x;
    const int fl = flag[0];
    float v[4], s = 0.f, sq = 0.f;
#pragma unroll
    for (int i = 0; i < 4; ++i) {
        long a = t * 1024 + tid + i * 256;
        v[i] = fl ? ((const float*)xin)[a] : bf2f(((const u16*)xin)[a]);
        s += v[i]; sq += v[i] * v[i];
    }
    for (int off = 32; off; off >>= 1) { s += __shfl_down(s, off, 64); sq += __shfl_down(sq, off, 64); }
    __shared__ float red[8];
    int lane = tid & 63, w = tid >> 6;
    if (!lane) { red[w] = s; red[4 + w] = sq; }
    __syncthreads();
    float S = red[0] + red[1] + red[2] + red[3];
    float SQ = red[4] + red[5] + red[6] + red[7];
    float mu = S * (1.f / 1024.f);
    float var = SQ * (1.f / 1024.f) - mu * mu;
    float rs = rsqrtf(var + 1e-5f);
#pragma unroll
    for (int i = 0; i < 4; ++i) {
        int col = tid + i * 256;
        XN[t * 1024 + col] = f2bf((v[i] - mu) * rs * bf2f(cv[5120 + col]) + bf2f(cv[6144 + col]));
    }
}

// ---------------- GEMM1: q(elu+1) | vT(coalesced) | fused k=elu(k*sig(g))+1 -> K + kT ----------------
__global__ __launch_bounds__(256) void k_gemm1(const u16* __restrict__ XN, const u16* __restrict__ Wt,
                                               const u16* __restrict__ cv,
                                               u16* __restrict__ Q, u16* __restrict__ K,
                                               u16* __restrict__ kT, u16* __restrict__ vT) {
    __shared__ u16 S[20480];   // gemm: As=S[0..8192), Bs=S[8192..16384); epilogue unions below
    const int tid = threadIdx.x, bid = blockIdx.x;
    const int nt = bid & 31, mt = bid >> 5;
    f32x4 acc[4][4]; ZERO_ACC(acc);
    gemm_loop(XN, (long)mt * 128, 1024, 0, Wt, (long)nt * 128, 1024, 0, 16, S, S + 8192, tid, acc);
    EPI_COORDS
    const long trow0 = (long)mt * 128;
    const int b = mt >> 5; const long tb0 = (long)(mt & 31) * 128;
    if (nt < 8) {              // ---- q: elu+1, row-major ----
#pragma unroll
        for (int mi = 0; mi < 4; ++mi)
#pragma unroll
            for (int ni = 0; ni < 4; ++ni) {
                int d = nt * 128 + waveN * 64 + ni * 16 + l16;
                float bias = bf2f(cv[d]);
                int row0 = waveM * 64 + mi * 16 + quad * 4;
#pragma unroll
                for (int r = 0; r < 4; ++r) {
                    float v = acc[mi][ni][r] + bias;
                    v = v > 0.f ? v + 1.f : expf(v);
                    Q[(trow0 + row0 + r) * 1024 + d] = f2bf(v);
                }
            }
    } else if (nt < 16) {      // ---- v: stage [128 col][132 t] u16, coalesced vT write ----
        const int d0 = (nt - 8) * 128;
#pragma unroll
        for (int mi = 0; mi < 4; ++mi)
#pragma unroll
            for (int ni = 0; ni < 4; ++ni) {
                int col = waveN * 64 + ni * 16 + l16;
                float bias = bf2f(cv[2048 + d0 + col]);
#pragma unroll
                for (int r = 0; r < 4; ++r)
                    S[col * 132 + waveM * 64 + mi * 16 + quad * 4 + r] = f2bf(acc[mi][ni][r] + bias);
            }
        __syncthreads();
#pragma unroll
        for (int i = 0; i < 16; ++i) {
            int ch = tid + i * 256;                 // 4096 chunks of 4 u16
            int col = ch >> 5, t4 = (ch & 31) * 4;
            uint2 val = *(const uint2*)(S + col * 132 + t4);
            *(uint2*)(vT + (long)b * 4194304 + (long)(d0 + col) * 4096 + tb0 + t4) = val;
        }
    } else {                   // ---- kg pair p: cols 0-63 = k[d0+..], 64-127 = gate[d0+..] ----
        const int p = nt - 16; const int d0 = p * 64;
        u16* gS = S;           // [128][66] u16 sigmoid(gate)
        u16* kS = S + 8448;    // [64][132] u16 activated k (for kT)
        if (waveN == 1) {      // gate half
#pragma unroll
            for (int mi = 0; mi < 4; ++mi)
#pragma unroll
                for (int ni = 0; ni < 4; ++ni) {
                    int col = ni * 16 + l16;
                    float bias = bf2f(cv[3072 + d0 + col]);
#pragma unroll
                    for (int r = 0; r < 4; ++r) {
                        int row = waveM * 64 + mi * 16 + quad * 4 + r;
                        float g = acc[mi][ni][r] + bias;
                        gS[row * 66 + col] = f2bf(1.f / (1.f + expf(-g)));
                    }
                }
        }
        __syncthreads();
        if (waveN == 0) {      // k half: activate, write K row-major + stage for kT
#pragma unroll
            for (int mi = 0; mi < 4; ++mi)
#pragma unroll
                for (int ni = 0; ni < 4; ++ni) {
                    int col = ni * 16 + l16;
                    float bias = bf2f(cv[1024 + d0 + col]);
#pragma unroll
                    for (int r = 0; r < 4; ++r) {
                        int row = waveM * 64 + mi * 16 + quad * 4 + r;
                        float kk = (acc[mi][ni][r] + bias) * bf2f(gS[row * 66 + col]);
                        kk = kk > 0.f ? kk + 1.f : expf(kk);
                        u16 kb = f2bf(kk);
                        K[(trow0 + row) * 1024 + d0 + col] = kb;
                        kS[col * 132 + row] = kb;
                    }
                }
        }
        __syncthreads();
#pragma unroll
        for (int i = 0; i < 8; ++i) {              // 2048 chunks: [64 d][128 t]
            int ch = tid + i * 256;
            int col = ch >> 5, t4 = (ch & 31) * 4;
            uint2 val = *(const uint2*)(kS + col * 132 + t4);
            *(uint2*)(kT + (long)b * 4194304 + (long)(d0 + col) * 4096 + tb0 + t4) = val;
        }
    }
}

// ---------------- per-chunk k sums: csum[b][c][d] ----------------
__global__ __launch_bounds__(256) void k_csum(const u16* __restrict__ K, float* __restrict__ csum) {
    const int bid = blockIdx.x, tid = threadIdx.x;   // 64 blocks
    const int b = bid >> 4, c = (bid >> 2) & 3, dg = bid & 3;
    const int d = dg * 256 + tid;
    const u16* base = K + ((long)b * 4096 + c * 1024) * 1024 + d;
    float s = 0.f;
    for (int t = 0; t < 1024; ++t) s += bf2f(base[(long)t * 1024]);
    csum[((b * 4 + c) << 10) + d] = s;
}

// ---------------- pass1: ST[b][c][d][e] = sum_s v[s,d] k[s,e] ----------------
__global__ __launch_bounds__(256) void k_pass1(const u16* __restrict__ kT, const u16* __restrict__ vT,
                                               u16* __restrict__ ST) {
    __shared__ u16 S[16384];
    const int tid = threadIdx.x, bid = blockIdx.x;
    const int tile = bid & 63, c = (bid >> 6) & 3, b = bid >> 8;
    const int dt = tile >> 3, et = tile & 7;
    f32x4 acc[4][4]; ZERO_ACC(acc);
    gemm_loop(vT + (long)b * 4194304, (long)dt * 128, 4096, (long)c * 1024,
              kT + (long)b * 4194304, (long)et * 128, 4096, (long)c * 1024, 16, S, S + 8192, tid, acc);
    EPI_COORDS
    u16* dst = ST + ((long)(b * 4 + c) << 20);
#pragma unroll
    for (int mi = 0; mi < 4; ++mi)
#pragma unroll
        for (int ni = 0; ni < 4; ++ni)
#pragma unroll
            for (int r = 0; r < 4; ++r) {
                long d = dt * 128 + waveM * 64 + mi * 16 + quad * 4 + r;
                long e = et * 128 + waveN * 64 + ni * 16 + l16;
                dst[d * 1024 + e] = f2bf(acc[mi][ni][r]);
            }
}

// ---------------- in-place exclusive prefix over chunk states ----------------
__global__ __launch_bounds__(256) void k_stpre(u16* __restrict__ ST) {
    const long gid = (long)blockIdx.x * 256 + threadIdx.x;  // 4M
    const int b = (int)(gid >> 20); const long rem = gid & 0xFFFFF;
    float run = 0.f;
    for (int c = 0; c < 4; ++c) {
        long a = (((long)(b * 4 + c)) << 20) + rem;
        float v = bf2f(ST[a]);
        ST[a] = f2bf(run);
        run += v;
    }
}

// ---------------- pass2a: P[t, s_local] = masked q_t . k_s (intra chunk) ----------------
__global__ __launch_bounds__(256) void k_pass2a(const u16* __restrict__ Q, const u16* __restrict__ K,
                                                u16* __restrict__ P) {
    const int tid = threadIdx.x, bid = blockIdx.x;
    const int tile = bid & 63, c = (bid >> 6) & 3, b = bid >> 8;
    const int ti = tile >> 3, si = tile & 7;
    const long trow0 = (long)b * 4096 + c * 1024 + ti * 128;
    if (si > ti) {  // strictly-upper tile: zeros (block-uniform)
#pragma unroll
        for (int i = 0; i < 64; ++i) {
            int idx = tid + i * 256; int rr = idx >> 7, cc = idx & 127;
            P[(trow0 + rr) * 1024 + si * 128 + cc] = 0;
        }
        return;
    }
    __shared__ u16 S[16384];
    const long srow0 = (long)b * 4096 + c * 1024 + si * 128;
    f32x4 acc[4][4]; ZERO_ACC(acc);
    gemm_loop(Q, trow0, 1024, 0, K, srow0, 1024, 0, 16, S, S + 8192, tid, acc);
    EPI_COORDS
#pragma unroll
    for (int mi = 0; mi < 4; ++mi)
#pragma unroll
        for (int ni = 0; ni < 4; ++ni) {
            int slc = si * 128 + waveN * 64 + ni * 16 + l16;
#pragma unroll
            for (int r = 0; r < 4; ++r) {
                int tl = waveM * 64 + mi * 16 + quad * 4 + r;
                float v = (ti * 128 + tl >= slc) ? acc[mi][ni][r] : 0.f;
                P[(trow0 + tl) * 1024 + slc] = f2bf(v);
            }
        }
}

// ---------------- den[t] = q_t . chunk_prefix + rowsum(P) + eps ----------------
__global__ __launch_bounds__(256) void k_den(const u16* __restrict__ Q, const u16* __restrict__ P,
                                             const float* __restrict__ csum, float* __restrict__ den) {
    const long t = blockIdx.x; const int tid = threadIdx.x;
    const int b = (int)(t >> 12), c = (int)((t >> 10) & 3);
    float s = 0.f;
#pragma unroll
    for (int i = 0; i < 4; ++i) {
        int e = tid + i * 256;
        float kp = 0.f;
        for (int cp = 0; cp < c; ++cp) kp += csum[((b * 4 + cp) << 10) + e];
        s += bf2f(Q[t * 1024 + e]) * kp + bf2f(P[t * 1024 + e]);
    }
    for (int off = 32; off; off >>= 1) s += __shfl_down(s, off, 64);
    __shared__ float red[4];
    int lane = tid & 63, w = tid >> 6;
    if (!lane) red[w] = s;
    __syncthreads();
    if (!tid) den[t] = red[0] + red[1] + red[2] + red[3] + 1e-6f;
}

// ---------------- pass2b: y[t,d] = (q@ST_prefix + P@V)/den ----------------
__global__ __launch_bounds__(256) void k_pass2b(const u16* __restrict__ Q, const u16* __restrict__ ST,
                                                const u16* __restrict__ P, const u16* __restrict__ vT,
                                                const float* __restrict__ den, u16* __restrict__ Yb) {
    __shared__ u16 S[16384];
    const int tid = threadIdx.x, bid = blockIdx.x;
    const int tile = bid & 63, c = (bid >> 6) & 3, b = bid >> 8;
    const int ti = tile >> 3, di = tile & 7;
    const long trow0 = (long)b * 4096 + c * 1024 + ti * 128;
    f32x4 acc[4][4]; ZERO_ACC(acc);
    if (c > 0)  // inter-chunk (prefix is zero for c==0)
        gemm_loop(Q, trow0, 1024, 0, ST + ((long)(b * 4 + c) << 20), (long)di * 128, 1024, 0,
                  16, S, S + 8192, tid, acc);
    // intra-chunk: only s-tiles <= ti carry mass (P upper region zeroed)
    gemm_loop(P, trow0, 1024, 0, vT + (long)b * 4194304, (long)di * 128, 4096, (long)c * 1024,
              (ti + 1) * 2, S, S + 8192, tid, acc);
    EPI_COORDS
#pragma unroll
    for (int mi = 0; mi < 4; ++mi)
#pragma unroll
        for (int ni = 0; ni < 4; ++ni) {
            long d = di * 128 + waveN * 64 + ni * 16 + l16;
#pragma unroll
            for (int r = 0; r < 4; ++r) {
                long t = trow0 + waveM * 64 + mi * 16 + quad * 4 + r;
                Yb[t * 1024 + d] = f2bf(acc[mi][ni][r] / den[t]);
            }
        }
}

// ---------------- proj: out = y @ w_proj + b_proj (dtype-aware store) ----------------
__global__ __launch_bounds__(256) void k_proj(const u16* __restrict__ Yb, const u16* __restrict__ WpT,
                                              const u16* __restrict__ cv, const int* __restrict__ flag,
                                              void* __restrict__ out) {
    __shared__ u16 S[16384];
    const int tid = threadIdx.x, bid = blockIdx.x;
    const int nt = bid & 7, mt = bid >> 3;
    f32x4 acc[4][4]; ZERO_ACC(acc);
    gemm_loop(Yb, (long)mt * 128, 1024, 0, WpT, (long)nt * 128, 1024, 0, 16, S, S + 8192, tid, acc);
    EPI_COORDS
    const int fl = flag[0];
#pragma unroll
    for (int mi = 0; mi < 4; ++mi)
#pragma unroll
        for (int ni = 0; ni < 4; ++ni) {
            long col = nt * 128 + waveN * 64 + ni * 16 + l16;
            float bias = bf2f(cv[4096 + col]);
#pragma unroll
            for (int r = 0; r < 4; ++r) {
                long row = mt * 128 + waveM * 64 + mi * 16 + quad * 4 + r;
                float v = acc[mi][ni][r] + bias;
                if (fl) ((float*)out)[row * 1024 + col] = v;
                else    ((u16*)out)[row * 1024 + col] = f2bf(v);
            }
        }
}

// ---------------- fallback: report ws_size via output constant ----------------
__global__ __launch_bounds__(256) void k_fb(u16* __restrict__ out, long n, float val) {
    long i = (long)blockIdx.x * 256 + threadIdx.x;
    if (i < n) out[i] = f2bf(val);
}

extern "C" void kernel_launch(void* const* d_in, const int* in_sizes, int n_in,
                              void* d_out, int out_size, void* d_ws, size_t ws_size,
                              hipStream_t stream) {
    const void* x     = d_in[0];
    const void* wqkv  = d_in[1];
    const void* bqkv  = d_in[2];
    const void* wgate = d_in[3];
    const void* bgate = d_in[4];
    const void* wproj = d_in[5];
    const void* bproj = d_in[6];
    const void* lng   = d_in[7];
    const void* lnb   = d_in[8];

    const long NEEDED = 178403336L;   // ~170.1 MB
    if (ws_size < (size_t)NEEDED) {
        k_fb<<<(int)((out_size + 255) / 256), 256, 0, stream>>>((u16*)d_out, out_size, (float)(ws_size >> 20));
        return;
    }

    char* w = (char*)d_ws;
    u16* XN  = (u16*)(w);                 // 32MB; dead after gemm1
    u16* ST  = XN;                        // alias (written by pass1)
    u16* Q   = (u16*)(w + 33554432L);     // 32MB elu(q)+1
    u16* K   = (u16*)(w + 67108864L);     // 32MB activated k; dead after pass2a/den
    u16* Yb  = K;                         // alias (written by pass2b)
    u16* kT  = (u16*)(w + 100663296L);    // 32MB [4][1024][4096]; dead after pass1
    u16* P   = kT;                        // alias (written by pass2a)
    u16* vT  = (u16*)(w + 134217728L);    // 32MB [4][1024][4096]
    u16* Wt  = (u16*)(w + 167772160L);    // 8MB  [4096,1024] permuted order
    u16* WpT = (u16*)(w + 176160768L);    // 2MB  [1024,1024]
    float* csum = (float*)(w + 178257920L);  // 64KB [16][1024]
    float* den  = (float*)(w + 178323456L);  // 64KB [16384]
    u16* cv     = (u16*)(w + 178388992L);    // 14KB
    int* flag   = (int*)(w + 178403328L);    // 4B

    k_detect<<<1,     256, 0, stream>>>((const u16*)wqkv, flag);
    k_cvec  <<<28,    256, 0, stream>>>(bqkv, bgate, bproj, lng, lnb, flag, cv);
    k_transw<<<1280,  256, 0, stream>>>(wqkv, wgate, wproj, flag, Wt, WpT);
    k_ln    <<<16384, 256, 0, stream>>>(x, cv, flag, XN);
    k_gemm1 <<<4096,  256, 0, stream>>>(XN, Wt, cv, Q, K, kT, vT);
    k_csum  <<<64,    256, 0, stream>>>(K, csum);
    k_pass1 <<<1024,  256, 0, stream>>>(kT, vT, ST);
    k_stpre <<<16384, 256, 0, stream>>>(ST);
    k_pass2a<<<1024,  256, 0, stream>>>(Q, K, P);
    k_den   <<<16384, 256, 0, stream>>>(Q, P, csum, den);
    k_pass2b<<<1024,  256, 0, stream>>>(Q, ST, P, vT, den, Yb);
    k_proj  <<<1024,  256, 0, stream>>>(Yb, WpT, cv, flag, d_out);
}